// Round 1
// baseline (79.848 us; speedup 1.0000x reference)
//
#include <hip/hip_runtime.h>

// Embedding gather: out[row, :] = table[idx[row], :]
//   rows   = BATCH*SLOTS*NNZ = 4096*26*8 = 851,968
//   EMB    = 64 floats = 256 B per row = 16 float4
// Layout: 16 lanes per row, each lane moves one float4 (16 B).
// Block 256 threads handles 16 rows.

#define NROWS (4096 * 26 * 8)
#define F4_PER_ROW 16   // 64 floats / 4

__global__ __launch_bounds__(256)
void All2AllDenseEmbedding_76828374991711_kernel(const int* __restrict__ idx,
                                                 const float4* __restrict__ table,
                                                 float4* __restrict__ out) {
    unsigned gid = blockIdx.x * 256u + threadIdx.x;
    unsigned row = gid >> 4;      // which output row
    unsigned col = gid & 15u;     // which float4 within the row
    if (row < NROWS) {
        size_t r = (size_t)(unsigned)idx[row];           // table row (0 .. 1M-1)
        out[(size_t)row * F4_PER_ROW + col] = table[r * F4_PER_ROW + col];
    }
}

extern "C" void kernel_launch(void* const* d_in, const int* in_sizes, int n_in,
                              void* d_out, int out_size, void* d_ws, size_t ws_size,
                              hipStream_t stream) {
    const int*    idx   = (const int*)d_in[0];     // inputs [B,S,N] int32
    const float4* table = (const float4*)d_in[1];  // table  [VOCAB, 64] f32
    float4*       out   = (float4*)d_out;          // [B,S,N,64] f32

    unsigned total_threads = NROWS * F4_PER_ROW;   // one thread per float4
    unsigned grid = (total_threads + 255) / 256;
    All2AllDenseEmbedding_76828374991711_kernel<<<grid, 256, 0, stream>>>(idx, table, out);
}

// Round 3
// 67.566 us; speedup vs baseline: 1.1818x; 1.1818x over previous
//
#include <hip/hip_runtime.h>

// Embedding gather: out[row, :] = table[idx[row], :]
//   rows   = BATCH*SLOTS*NNZ = 4096*26*8 = 851,968
//   EMB    = 64 floats = 256 B per row = 16 float4
// Layout: 16 lanes per row, each lane moves one float4 (16 B).
// Block 256 threads handles 16 rows.
//
// R2: nontemporal output stores via clang native vector type
// (__builtin_nontemporal_store rejects HIP_vector_type). Keeps the 218 MB
// write stream from evicting the ~L3-resident 256 MB table, so duplicate
// index rows (~280K of 852K) stay L3 hits -> lower FETCH_SIZE.

#define NROWS (4096 * 26 * 8)
#define F4_PER_ROW 16   // 64 floats / 4

typedef float vfloat4 __attribute__((ext_vector_type(4)));

__global__ __launch_bounds__(256)
void All2AllDenseEmbedding_76828374991711_kernel(const int* __restrict__ idx,
                                                 const vfloat4* __restrict__ table,
                                                 vfloat4* __restrict__ out) {
    unsigned gid = blockIdx.x * 256u + threadIdx.x;
    unsigned row = gid >> 4;      // which output row
    unsigned col = gid & 15u;     // which float4 within the row
    if (row < NROWS) {
        size_t r = (size_t)(unsigned)idx[row];           // table row (0 .. 1M-1)
        vfloat4 v = table[r * F4_PER_ROW + col];         // cached read (want L3 hits)
        __builtin_nontemporal_store(v, &out[(size_t)row * F4_PER_ROW + col]);
    }
}

extern "C" void kernel_launch(void* const* d_in, const int* in_sizes, int n_in,
                              void* d_out, int out_size, void* d_ws, size_t ws_size,
                              hipStream_t stream) {
    const int*     idx   = (const int*)d_in[0];      // inputs [B,S,N] int32
    const vfloat4* table = (const vfloat4*)d_in[1];  // table  [VOCAB, 64] f32
    vfloat4*       out   = (vfloat4*)d_out;          // [B,S,N,64] f32

    unsigned total_threads = NROWS * F4_PER_ROW;     // one thread per float4
    unsigned grid = (total_threads + 255) / 256;
    All2AllDenseEmbedding_76828374991711_kernel<<<grid, 256, 0, stream>>>(idx, table, out);
}